// Round 2
// baseline (15996.828 us; speedup 1.0000x reference)
//
#include <hip/hip_runtime.h>
#include <hip/hip_fp16.h>

#define BSZ   64
#define ILEN  1024
#define TLEN  1024
#define TTOT  2048
#define IDIM  128
#define HDIM  256
#define GDIM  1024   // 4*HDIM
#define NCLS  128

typedef unsigned int u32;
typedef _Float16 h2_t __attribute__((ext_vector_type(2)));

__device__ __forceinline__ float fdot2(u32 a, u32 b, float acc) {
#if __has_builtin(__builtin_amdgcn_fdot2)
    union { u32 u; h2_t h; } ua, ub;
    ua.u = a; ub.u = b;
    return __builtin_amdgcn_fdot2(ua.h, ub.h, acc, false);
#else
    union { u32 u; __half2 h; } ua, ub;
    ua.u = a; ub.u = b;
    return acc + __low2float(ua.h) * __low2float(ub.h)
               + __high2float(ua.h) * __high2float(ub.h);
#endif
}

__device__ __forceinline__ u32 packf2(float x, float y) {
    __half2 h = __floats2half2_rn(x, y);
    union { __half2 h; u32 u; } c; c.h = h;
    return c.u;
}

__device__ __forceinline__ float sigm(float x) { return 1.f / (1.f + __expf(-x)); }
__device__ __forceinline__ float tanh_fast(float x) { return 1.f - 2.f / (__expf(2.f * x) + 1.f); }

// ---------------------------------------------------------------------------
// Pack fp32 weights into f16 pairs, TRANSPOSED layout [k4][row] so that a
// wave's 64 lanes (consecutive rows) load 64 consecutive uint4 (coalesced).
//   Whq: uint4[32][1024]   element [k4][j] = w_hh[j][8k4 .. 8k4+7]
//   Wiq: uint4[16][1024]   element [k4][j] = w_ih[j][8k4 .. 8k4+7]
//   Wcq: uint4[32][128]    element [k4][n] = clf_w[n][8k4 .. 8k4+7]
// ---------------------------------------------------------------------------
__global__ void pack_kernel(const float* __restrict__ w_ih,
                            const float* __restrict__ w_hh,
                            const float* __restrict__ clf_w,
                            uint4* __restrict__ Whq,
                            uint4* __restrict__ Wiq,
                            uint4* __restrict__ Wcq)
{
    int i = blockIdx.x * blockDim.x + threadIdx.x;
    if (i < 32 * GDIM) {
        int j = i & (GDIM - 1);
        int k4 = i >> 10;
        const float* src = w_hh + (size_t)j * HDIM + k4 * 8;
        uint4 v;
        v.x = packf2(src[0], src[1]); v.y = packf2(src[2], src[3]);
        v.z = packf2(src[4], src[5]); v.w = packf2(src[6], src[7]);
        Whq[i] = v;
    } else if (i < 48 * GDIM) {
        int r = i - 32 * GDIM;
        int j = r & (GDIM - 1);
        int k4 = r >> 10;
        const float* src = w_ih + (size_t)j * IDIM + k4 * 8;
        uint4 v;
        v.x = packf2(src[0], src[1]); v.y = packf2(src[2], src[3]);
        v.z = packf2(src[4], src[5]); v.w = packf2(src[6], src[7]);
        Wiq[r] = v;
    } else if (i < 48 * GDIM + 32 * NCLS) {
        int r = i - 48 * GDIM;
        int n = r & (NCLS - 1);
        int k4 = r >> 7;
        const float* src = clf_w + (size_t)n * HDIM + k4 * 8;
        uint4 v;
        v.x = packf2(src[0], src[1]); v.y = packf2(src[2], src[3]);
        v.z = packf2(src[4], src[5]); v.w = packf2(src[6], src[7]);
        Wcq[r] = v;
    }
}

// ---------------------------------------------------------------------------
// Recurrent kernel: one block per batch element, thread j owns gate-row j.
// NEW in R2: the f16 weight rows live in REGISTERS (loaded once before the
// time loop) -- w_hh row = 32 uint4, w_ih row = 16 uint4, ~240 VGPRs/thread.
// Steady-state loop reads only h (LDS broadcast) and x_t (512 B/step).
// ---------------------------------------------------------------------------
__global__ __launch_bounds__(1024, 4) void lstm_rec(
    const float* __restrict__ inp,
    const float* __restrict__ bias_g,
    const uint4* __restrict__ Whq,
    const uint4* __restrict__ Wiq,
    __half* __restrict__ Hs)
{
    __shared__ alignas(16) __half h_sh[HDIM];    // 512 B
    __shared__ alignas(16) u32 x_sh[IDIM / 2];   // 512 B
    __shared__ float z_sh[GDIM];                 // 4 KB

    const int bb = blockIdx.x;
    const int j  = threadIdx.x;
    const float bj = bias_g[j];

    // hoist weights: loop-invariant, coalesced (lane j -> consecutive uint4)
    uint4 wh[32];
    uint4 wi[16];
    #pragma unroll
    for (int k4 = 0; k4 < 32; ++k4) wh[k4] = Whq[k4 * GDIM + j];
    #pragma unroll
    for (int k4 = 0; k4 < 16; ++k4) wi[k4] = Wiq[k4 * GDIM + j];

    float c = 0.f;
    if (j < HDIM) h_sh[j] = __float2half(0.f);
    const float2* xbase = (const float2*)(inp + (size_t)bb * ILEN * IDIM);

    for (int t = 0; t < TTOT; ++t) {
        if (t < ILEN && j < IDIM / 2) {
            float2 xv = xbase[(size_t)t * (IDIM / 2) + j];
            x_sh[j] = packf2(xv.x, xv.y);
        }
        __syncthreads();   // x ready; h from previous step ready

        float a0 = bj, a1 = 0.f, a2 = 0.f, a3 = 0.f;
        const uint4* hp = (const uint4*)h_sh;
        #pragma unroll
        for (int k4 = 0; k4 < HDIM / 8; ++k4) {
            uint4 h4 = hp[k4];           // broadcast ds_read_b128
            a0 = fdot2(wh[k4].x, h4.x, a0);
            a1 = fdot2(wh[k4].y, h4.y, a1);
            a2 = fdot2(wh[k4].z, h4.z, a2);
            a3 = fdot2(wh[k4].w, h4.w, a3);
        }
        if (t < ILEN) {
            const uint4* xp = (const uint4*)x_sh;
            #pragma unroll
            for (int k4 = 0; k4 < IDIM / 8; ++k4) {
                uint4 x4 = xp[k4];
                a0 = fdot2(wi[k4].x, x4.x, a0);
                a1 = fdot2(wi[k4].y, x4.y, a1);
                a2 = fdot2(wi[k4].z, x4.z, a2);
                a3 = fdot2(wi[k4].w, x4.w, a3);
            }
        }
        z_sh[j] = (a0 + a1) + (a2 + a3);
        __syncthreads();   // z ready; also: all h_sh reads done before overwrite

        if (j < HDIM) {
            float zi = z_sh[j];
            float zf = z_sh[j + HDIM];
            float zg = z_sh[j + 2 * HDIM];
            float zo = z_sh[j + 3 * HDIM];
            float ig = sigm(zi);
            float fg = sigm(zf);
            float gg = tanh_fast(zg);
            float og = sigm(zo);
            c = fg * c + ig * gg;
            float hn = og * tanh_fast(c);
            __half hh = __float2half(hn);
            h_sh[j] = hh;
            if (t >= ILEN) {
                Hs[((size_t)bb * TLEN + (t - ILEN)) * HDIM + j] = hh;
            }
        }
    }
}

// ---------------------------------------------------------------------------
// Classifier: out[b][t][n] = clf_b[n] + clf_w[n]·h[b][t].  Block handles one
// batch and 16 timesteps; H rows staged in LDS; Wcq streamed (L2-resident).
// ---------------------------------------------------------------------------
#define CTT 16
__global__ __launch_bounds__(256) void clf_kernel(
    const uint4* __restrict__ Wcq,
    const __half* __restrict__ Hs,
    const float* __restrict__ clf_b,
    float* __restrict__ out)
{
    __shared__ alignas(16) u32 h_sh[CTT * (HDIM / 2)];   // 8 KB
    const int tid = threadIdx.x;
    const int b  = blockIdx.x >> 6;            // TLEN/CTT = 64 tiles per batch
    const int t0 = (blockIdx.x & 63) * CTT;

    const uint4* hsrc = (const uint4*)(Hs + ((size_t)b * TLEN + t0) * HDIM);
    uint4* hdst = (uint4*)h_sh;
    hdst[tid]       = hsrc[tid];
    hdst[tid + 256] = hsrc[tid + 256];
    __syncthreads();

    const int n  = tid & (NCLS - 1);
    const int tl = tid >> 7;                   // 0 or 1
    const float bias = clf_b[n];
    float acc[8];
    #pragma unroll
    for (int q = 0; q < 8; ++q) acc[q] = bias;

    #pragma unroll 4
    for (int k4 = 0; k4 < HDIM / 8; ++k4) {
        uint4 w = Wcq[k4 * NCLS + n];
        #pragma unroll
        for (int q = 0; q < 8; ++q) {
            const uint4* hp = (const uint4*)(h_sh + (tl + 2 * q) * (HDIM / 2));
            uint4 h = hp[k4];
            acc[q] = fdot2(w.x, h.x, acc[q]);
            acc[q] = fdot2(w.y, h.y, acc[q]);
            acc[q] = fdot2(w.z, h.z, acc[q]);
            acc[q] = fdot2(w.w, h.w, acc[q]);
        }
    }
    #pragma unroll
    for (int q = 0; q < 8; ++q) {
        out[((size_t)b * TLEN + t0 + tl + 2 * q) * NCLS + n] = acc[q];
    }
}

// ---------------------------------------------------------------------------
extern "C" void kernel_launch(void* const* d_in, const int* in_sizes, int n_in,
                              void* d_out, int out_size, void* d_ws, size_t ws_size,
                              hipStream_t stream)
{
    const float* inp   = (const float*)d_in[0];
    // d_in[1] = tlen (1024, hardcoded)
    const float* w_ih  = (const float*)d_in[2];
    const float* w_hh  = (const float*)d_in[3];
    const float* bias  = (const float*)d_in[4];
    const float* clf_w = (const float*)d_in[5];
    const float* clf_b = (const float*)d_in[6];
    float* out = (float*)d_out;

    char* ws = (char*)d_ws;
    uint4*  Whq = (uint4*)(ws);                 // 512 KB
    uint4*  Wiq = (uint4*)(ws + 524288);        // 256 KB
    uint4*  Wcq = (uint4*)(ws + 786432);        // 64 KB
    __half* Hs  = (__half*)(ws + 851968);       // 33.55 MB

    pack_kernel<<<208, 256, 0, stream>>>(w_ih, w_hh, clf_w, Whq, Wiq, Wcq);
    lstm_rec<<<BSZ, 1024, 0, stream>>>(inp, bias, Whq, Wiq, Hs);
    clf_kernel<<<BSZ * (TLEN / CTT), 256, 0, stream>>>(Wcq, Hs, clf_b, out);
}

// Round 3
// 11593.541 us; speedup vs baseline: 1.3798x; 1.3798x over previous
//
#include <hip/hip_runtime.h>
#include <hip/hip_fp16.h>

#define BSZ   64
#define ILEN  1024
#define TLEN  1024
#define TTOT  2048
#define IDIM  128
#define HDIM  256
#define GDIM  1024   // 4*HDIM
#define NCLS  128
#define NSPLIT 4                 // blocks per batch element
#define UNITS_PB (HDIM / NSPLIT) // 64 hidden units per block
#define ROWS_PB  (GDIM / NSPLIT) // 256 gate rows per block

typedef unsigned int u32;
typedef _Float16 h2_t __attribute__((ext_vector_type(2)));

__device__ __forceinline__ float fdot2(u32 a, u32 b, float acc) {
#if __has_builtin(__builtin_amdgcn_fdot2)
    union { u32 u; h2_t h; } ua, ub;
    ua.u = a; ub.u = b;
    return __builtin_amdgcn_fdot2(ua.h, ub.h, acc, false);
#else
    union { u32 u; __half2 h; } ua, ub;
    ua.u = a; ub.u = b;
    return acc + __low2float(ua.h) * __low2float(ub.h)
               + __high2float(ua.h) * __high2float(ub.h);
#endif
}

__device__ __forceinline__ u32 packf2(float x, float y) {
    __half2 h = __floats2half2_rn(x, y);
    union { __half2 h; u32 u; } c; c.h = h;
    return c.u;
}

__device__ __forceinline__ float sigm(float x) { return 1.f / (1.f + __expf(-x)); }
__device__ __forceinline__ float tanh_fast(float x) { return 1.f - 2.f / (__expf(2.f * x) + 1.f); }

// ---------------------------------------------------------------------------
// Pack fp32 weights into f16 pairs, TRANSPOSED layout [k4][row].
// ---------------------------------------------------------------------------
__global__ void pack_kernel(const float* __restrict__ w_ih,
                            const float* __restrict__ w_hh,
                            const float* __restrict__ clf_w,
                            uint4* __restrict__ Whq,
                            uint4* __restrict__ Wiq,
                            uint4* __restrict__ Wcq)
{
    int i = blockIdx.x * blockDim.x + threadIdx.x;
    if (i < 32 * GDIM) {
        int j = i & (GDIM - 1);
        int k4 = i >> 10;
        const float* src = w_hh + (size_t)j * HDIM + k4 * 8;
        uint4 v;
        v.x = packf2(src[0], src[1]); v.y = packf2(src[2], src[3]);
        v.z = packf2(src[4], src[5]); v.w = packf2(src[6], src[7]);
        Whq[i] = v;
    } else if (i < 48 * GDIM) {
        int r = i - 32 * GDIM;
        int j = r & (GDIM - 1);
        int k4 = r >> 10;
        const float* src = w_ih + (size_t)j * IDIM + k4 * 8;
        uint4 v;
        v.x = packf2(src[0], src[1]); v.y = packf2(src[2], src[3]);
        v.z = packf2(src[4], src[5]); v.w = packf2(src[6], src[7]);
        Wiq[r] = v;
    } else if (i < 48 * GDIM + 32 * NCLS) {
        int r = i - 48 * GDIM;
        int n = r & (NCLS - 1);
        int k4 = r >> 7;
        const float* src = clf_w + (size_t)n * HDIM + k4 * 8;
        uint4 v;
        v.x = packf2(src[0], src[1]); v.y = packf2(src[2], src[3]);
        v.z = packf2(src[4], src[5]); v.w = packf2(src[6], src[7]);
        Wcq[r] = v;
    }
}

// ---------------------------------------------------------------------------
// Zero the cross-block h buffers and flags. Must run EVERY launch (workspace
// is poisoned 0xAA once and never restored; flags must start at 0).
// ---------------------------------------------------------------------------
__global__ void init_kernel(u32* __restrict__ hglob, u32* __restrict__ flags)
{
    int i = blockIdx.x * blockDim.x + threadIdx.x;
    if (i < BSZ * 2 * (HDIM / 2)) hglob[i] = 0u;
    if (i < BSZ * 32) flags[i] = 0u;
}

// ---------------------------------------------------------------------------
// Recurrent kernel, 4 blocks per batch element (cooperative launch).
// Block (b,q): owns hidden units [64q,64q+64), all 4 gates => 256 gate rows.
// Weights live in REGISTERS (192 VGPR/thread), loaded once.
// Cross-block h exchange via agent-scope atomics + per-batch flag counter.
// ---------------------------------------------------------------------------
__global__ __launch_bounds__(256, 1) void lstm_rec(
    const float* __restrict__ inp,
    const float* __restrict__ bias_g,
    const uint4* __restrict__ Whq,
    const uint4* __restrict__ Wiq,
    __half* __restrict__ Hs,
    u32* __restrict__ hglob,     // [BSZ][2][HDIM/2]
    u32* __restrict__ flags)     // [BSZ][32] (padded, one line per batch)
{
    __shared__ alignas(16) u32 h_sh[HDIM / 2];   // full h, f16-packed
    __shared__ alignas(16) u32 x_sh[IDIM / 2];
    __shared__ float z_sh[ROWS_PB];
    __shared__ __half hn_sh[UNITS_PB];

    const int blk = blockIdx.x;
    const int bb  = blk >> 2;     // batch
    const int q   = blk & 3;      // quarter of hidden units
    const int tid = threadIdx.x;
    const int u   = tid & (UNITS_PB - 1);   // 0..63
    const int g   = tid >> 6;               // gate 0..3 (i,f,g,o)
    const int j   = g * HDIM + q * UNITS_PB + u;   // global gate row

    const float bj = bias_g[j];

    // hoist weights into registers (loop-invariant, coalesced per wave)
    uint4 wh[32];
    #pragma unroll
    for (int k4 = 0; k4 < 32; ++k4) wh[k4] = Whq[k4 * GDIM + j];
    uint4 wi[16];
    #pragma unroll
    for (int k4 = 0; k4 < 16; ++k4) wi[k4] = Wiq[k4 * GDIM + j];

    float c = 0.f;
    if (tid < HDIM / 2) h_sh[tid] = 0u;

    u32* hg   = hglob + bb * (2 * (HDIM / 2));
    u32* flag = flags + bb * 32;
    const float2* xbase = (const float2*)(inp + (size_t)bb * ILEN * IDIM);

    for (int t = 0; t < TTOT; ++t) {
        if (t < ILEN && tid < IDIM / 2) {
            float2 xv = xbase[(size_t)t * (IDIM / 2) + tid];
            x_sh[tid] = packf2(xv.x, xv.y);
        }
        __syncthreads();   // x ready; h_sh (from prev exchange / init) ready

        float a0 = bj, a1 = 0.f, a2 = 0.f, a3 = 0.f;
        const uint4* hp = (const uint4*)h_sh;
        #pragma unroll
        for (int k4 = 0; k4 < HDIM / 8; ++k4) {
            uint4 h4 = hp[k4];            // broadcast read, conflict-free
            a0 = fdot2(wh[k4].x, h4.x, a0);
            a1 = fdot2(wh[k4].y, h4.y, a1);
            a2 = fdot2(wh[k4].z, h4.z, a2);
            a3 = fdot2(wh[k4].w, h4.w, a3);
        }
        if (t < ILEN) {
            const uint4* xp = (const uint4*)x_sh;
            #pragma unroll
            for (int k4 = 0; k4 < IDIM / 8; ++k4) {
                uint4 x4 = xp[k4];
                a0 = fdot2(wi[k4].x, x4.x, a0);
                a1 = fdot2(wi[k4].y, x4.y, a1);
                a2 = fdot2(wi[k4].z, x4.z, a2);
                a3 = fdot2(wi[k4].w, x4.w, a3);
            }
        }
        z_sh[tid] = (a0 + a1) + (a2 + a3);
        __syncthreads();   // z ready

        // wave 0 (tid<64) combines gates, updates c/h, publishes h slice
        if (tid < UNITS_PB) {
            float zi = z_sh[tid];
            float zf = z_sh[tid + UNITS_PB];
            float zg = z_sh[tid + 2 * UNITS_PB];
            float zo = z_sh[tid + 3 * UNITS_PB];
            float ig = sigm(zi);
            float fg = sigm(zf);
            float gg = tanh_fast(zg);
            float og = sigm(zo);
            c = fg * c + ig * gg;
            float hn = og * tanh_fast(c);
            __half hh = __float2half(hn);
            hn_sh[tid] = hh;
            if (t >= ILEN) {
                Hs[((size_t)bb * TLEN + (t - ILEN)) * HDIM + q * UNITS_PB + tid] = hh;
            }
        }
        // same wave: pack pairs and store to global h buffer (agent scope)
        if (tid < UNITS_PB / 2) {
            u32 v = ((const u32*)hn_sh)[tid];   // wave-local LDS RAW, hw-ordered
            __hip_atomic_store(&hg[((t + 1) & 1) * (HDIM / 2) + q * (UNITS_PB / 2) + tid],
                               v, __ATOMIC_RELAXED, __HIP_MEMORY_SCOPE_AGENT);
        }
        if (tid == 0) {
            // release: orders the 32 h-stores above (same wave, vmcnt-drained)
            __hip_atomic_fetch_add(flag, 1u, __ATOMIC_RELEASE, __HIP_MEMORY_SCOPE_AGENT);
            if (t + 1 < TTOT) {
                u32 target = (u32)NSPLIT * (u32)(t + 1);
                while (__hip_atomic_load(flag, __ATOMIC_ACQUIRE, __HIP_MEMORY_SCOPE_AGENT) < target) {
                    __builtin_amdgcn_s_sleep(1);
                }
            }
        }
        __syncthreads();   // all siblings done step t; safe to refresh h_sh

        if (t + 1 < TTOT) {
            if (tid < HDIM / 2) {
                h_sh[tid] = __hip_atomic_load(&hg[((t + 1) & 1) * (HDIM / 2) + tid],
                                              __ATOMIC_RELAXED, __HIP_MEMORY_SCOPE_AGENT);
            }
            // next iteration's first __syncthreads publishes h_sh block-wide
        }
    }
}

// ---------------------------------------------------------------------------
// Classifier: out[b][t][n] = clf_b[n] + clf_w[n]·h[b][t].
// ---------------------------------------------------------------------------
#define CTT 16
__global__ __launch_bounds__(256) void clf_kernel(
    const uint4* __restrict__ Wcq,
    const __half* __restrict__ Hs,
    const float* __restrict__ clf_b,
    float* __restrict__ out)
{
    __shared__ alignas(16) u32 h_sh[CTT * (HDIM / 2)];   // 8 KB
    const int tid = threadIdx.x;
    const int b  = blockIdx.x >> 6;
    const int t0 = (blockIdx.x & 63) * CTT;

    const uint4* hsrc = (const uint4*)(Hs + ((size_t)b * TLEN + t0) * HDIM);
    uint4* hdst = (uint4*)h_sh;
    hdst[tid]       = hsrc[tid];
    hdst[tid + 256] = hsrc[tid + 256];
    __syncthreads();

    const int n  = tid & (NCLS - 1);
    const int tl = tid >> 7;
    const float bias = clf_b[n];
    float acc[8];
    #pragma unroll
    for (int q = 0; q < 8; ++q) acc[q] = bias;

    #pragma unroll 4
    for (int k4 = 0; k4 < HDIM / 8; ++k4) {
        uint4 w = Wcq[k4 * NCLS + n];
        #pragma unroll
        for (int q = 0; q < 8; ++q) {
            const uint4* hp = (const uint4*)(h_sh + (tl + 2 * q) * (HDIM / 2));
            uint4 h = hp[k4];
            acc[q] = fdot2(w.x, h.x, acc[q]);
            acc[q] = fdot2(w.y, h.y, acc[q]);
            acc[q] = fdot2(w.z, h.z, acc[q]);
            acc[q] = fdot2(w.w, h.w, acc[q]);
        }
    }
    #pragma unroll
    for (int q = 0; q < 8; ++q) {
        out[((size_t)b * TLEN + t0 + tl + 2 * q) * NCLS + n] = acc[q];
    }
}

// ---------------------------------------------------------------------------
extern "C" void kernel_launch(void* const* d_in, const int* in_sizes, int n_in,
                              void* d_out, int out_size, void* d_ws, size_t ws_size,
                              hipStream_t stream)
{
    const float* inp   = (const float*)d_in[0];
    // d_in[1] = tlen (1024, hardcoded)
    const float* w_ih  = (const float*)d_in[2];
    const float* w_hh  = (const float*)d_in[3];
    const float* bias  = (const float*)d_in[4];
    const float* clf_w = (const float*)d_in[5];
    const float* clf_b = (const float*)d_in[6];
    float* out = (float*)d_out;

    char* ws = (char*)d_ws;
    uint4*  Whq   = (uint4*)(ws);                    // 512 KB
    uint4*  Wiq   = (uint4*)(ws + 524288);           // 256 KB
    uint4*  Wcq   = (uint4*)(ws + 786432);           // 64 KB
    __half* Hs    = (__half*)(ws + 851968);          // 33.55 MB
    u32*    hglob = (u32*)(ws + 851968 + 33554432);  // 64 KB
    u32*    flags = (u32*)(ws + 851968 + 33554432 + 65536);  // 8 KB

    init_kernel<<<64, 256, 0, stream>>>(hglob, flags);
    pack_kernel<<<208, 256, 0, stream>>>(w_ih, w_hh, clf_w, Whq, Wiq, Wcq);

    void* args[] = {(void*)&inp, (void*)&bias, (void*)&Whq, (void*)&Wiq,
                    (void*)&Hs, (void*)&hglob, (void*)&flags};
    hipLaunchCooperativeKernel((const void*)lstm_rec,
                               dim3(BSZ * NSPLIT), dim3(256), args, 0, stream);

    clf_kernel<<<BSZ * (TLEN / CTT), 256, 0, stream>>>(Wcq, Hs, clf_b, out);
}

// Round 4
// 9850.658 us; speedup vs baseline: 1.6239x; 1.1769x over previous
//
#include <hip/hip_runtime.h>
#include <hip/hip_fp16.h>

#define BSZ   64
#define ILEN  1024
#define TLEN  1024
#define TTOT  2048
#define IDIM  128
#define HDIM  256
#define GDIM  1024   // 4*HDIM
#define NCLS  128
#define NSPLIT 4                 // blocks per batch element
#define UNITS_PB (HDIM / NSPLIT) // 64 hidden units per block
#define ROWS_PB  (GDIM / NSPLIT) // 256 gate rows per block

typedef unsigned int u32;
typedef _Float16 h2_t __attribute__((ext_vector_type(2)));

__device__ __forceinline__ float fdot2(u32 a, u32 b, float acc) {
#if __has_builtin(__builtin_amdgcn_fdot2)
    union { u32 u; h2_t h; } ua, ub;
    ua.u = a; ub.u = b;
    return __builtin_amdgcn_fdot2(ua.h, ub.h, acc, false);
#else
    union { u32 u; __half2 h; } ua, ub;
    ua.u = a; ub.u = b;
    return acc + __low2float(ua.h) * __low2float(ub.h)
               + __high2float(ua.h) * __high2float(ub.h);
#endif
}

__device__ __forceinline__ u32 packf2(float x, float y) {
    __half2 h = __floats2half2_rn(x, y);
    union { __half2 h; u32 u; } c; c.h = h;
    return c.u;
}

__device__ __forceinline__ float sigm(float x) { return 1.f / (1.f + __expf(-x)); }
__device__ __forceinline__ float tanh_fast(float x) { return 1.f - 2.f / (__expf(2.f * x) + 1.f); }

// ---------------------------------------------------------------------------
// Pack fp32 weights into f16 pairs, TRANSPOSED layout [k4][row].
// ---------------------------------------------------------------------------
__global__ void pack_kernel(const float* __restrict__ w_ih,
                            const float* __restrict__ w_hh,
                            const float* __restrict__ clf_w,
                            uint4* __restrict__ Whq,
                            uint4* __restrict__ Wiq,
                            uint4* __restrict__ Wcq)
{
    int i = blockIdx.x * blockDim.x + threadIdx.x;
    if (i < 32 * GDIM) {
        int j = i & (GDIM - 1);
        int k4 = i >> 10;
        const float* src = w_hh + (size_t)j * HDIM + k4 * 8;
        uint4 v;
        v.x = packf2(src[0], src[1]); v.y = packf2(src[2], src[3]);
        v.z = packf2(src[4], src[5]); v.w = packf2(src[6], src[7]);
        Whq[i] = v;
    } else if (i < 48 * GDIM) {
        int r = i - 32 * GDIM;
        int j = r & (GDIM - 1);
        int k4 = r >> 10;
        const float* src = w_ih + (size_t)j * IDIM + k4 * 8;
        uint4 v;
        v.x = packf2(src[0], src[1]); v.y = packf2(src[2], src[3]);
        v.z = packf2(src[4], src[5]); v.w = packf2(src[6], src[7]);
        Wiq[r] = v;
    } else if (i < 48 * GDIM + 32 * NCLS) {
        int r = i - 48 * GDIM;
        int n = r & (NCLS - 1);
        int k4 = r >> 7;
        const float* src = clf_w + (size_t)n * HDIM + k4 * 8;
        uint4 v;
        v.x = packf2(src[0], src[1]); v.y = packf2(src[2], src[3]);
        v.z = packf2(src[4], src[5]); v.w = packf2(src[6], src[7]);
        Wcq[r] = v;
    }
}

// ---------------------------------------------------------------------------
// Zero the cross-block h buffers and flags. Must run EVERY launch (workspace
// is poisoned 0xAA once and never restored; flags must start at 0).
// ---------------------------------------------------------------------------
__global__ void init_kernel(u32* __restrict__ hglob, u32* __restrict__ flags)
{
    int i = blockIdx.x * blockDim.x + threadIdx.x;
    if (i < BSZ * 2 * (HDIM / 2)) hglob[i] = 0u;
    if (i < BSZ * 32) flags[i] = 0u;
}

// ---------------------------------------------------------------------------
// Recurrent kernel, 4 blocks per batch element (cooperative launch).
// Block (b,q): owns hidden units [64q,64q+64), all 4 gates => 256 gate rows.
// Weights PINNED in registers via asm (compiler cannot rematerialize).
// Sibling blocks are stride-64 in blockIdx so they share an XCD under
// round-robin dispatch (64 % 8 == 0) -- sync stays in one L2.
// ---------------------------------------------------------------------------
__global__ __launch_bounds__(256, 1) void lstm_rec(
    const float* __restrict__ inp,
    const float* __restrict__ bias_g,
    const uint4* __restrict__ Whq,
    const uint4* __restrict__ Wiq,
    __half* __restrict__ Hs,
    u32* __restrict__ hglob,     // [BSZ][2][HDIM/2]
    u32* __restrict__ flags)     // [BSZ][32] (padded, one line per batch)
{
    __shared__ alignas(16) u32 h_sh[HDIM / 2];   // full h, f16-packed
    __shared__ alignas(16) u32 x_sh[IDIM / 2];
    __shared__ float z_sh[ROWS_PB];
    __shared__ __half hn_sh[UNITS_PB];

    const int blk = blockIdx.x;
    const int bb  = blk & 63;     // batch   (siblings stride 64 -> same XCD)
    const int q   = blk >> 6;     // quarter of hidden units
    const int tid = threadIdx.x;
    const int u   = tid & (UNITS_PB - 1);   // 0..63
    const int g   = tid >> 6;               // gate 0..3 (i,f,g,o)
    const int j   = g * HDIM + q * UNITS_PB + u;   // global gate row

    const float bj = bias_g[j];

    // hoist weights into registers and PIN them (forbid rematerialization)
    uint4 wh[32];
    #pragma unroll
    for (int k4 = 0; k4 < 32; ++k4) wh[k4] = Whq[k4 * GDIM + j];
    uint4 wi[16];
    #pragma unroll
    for (int k4 = 0; k4 < 16; ++k4) wi[k4] = Wiq[k4 * GDIM + j];
    #pragma unroll
    for (int k4 = 0; k4 < 32; ++k4)
        asm volatile("" : "+v"(wh[k4].x), "+v"(wh[k4].y), "+v"(wh[k4].z), "+v"(wh[k4].w));
    #pragma unroll
    for (int k4 = 0; k4 < 16; ++k4)
        asm volatile("" : "+v"(wi[k4].x), "+v"(wi[k4].y), "+v"(wi[k4].z), "+v"(wi[k4].w));

    float c = 0.f;
    if (tid < HDIM / 2) h_sh[tid] = 0u;

    u32* hg   = hglob + bb * (2 * (HDIM / 2));
    u32* flag = flags + bb * 32;
    const float2* xbase = (const float2*)(inp + (size_t)bb * ILEN * IDIM);

    // prefetch x_0
    float2 xv = make_float2(0.f, 0.f);
    if (tid < IDIM / 2) xv = xbase[tid];

    for (int t = 0; t < TTOT; ++t) {
        if (t < ILEN && tid < IDIM / 2) {
            x_sh[tid] = packf2(xv.x, xv.y);
        }
        __syncthreads();   // x ready; h_sh (from prev exchange / init) ready

        // issue prefetch of x_{t+1}; completes under the compute below
        if (t + 1 < ILEN && tid < IDIM / 2) {
            xv = xbase[(size_t)(t + 1) * (IDIM / 2) + tid];
        }

        float a0 = bj, a1 = 0.f, a2 = 0.f, a3 = 0.f;
        const uint4* hp = (const uint4*)h_sh;
        #pragma unroll
        for (int k4 = 0; k4 < HDIM / 8; ++k4) {
            uint4 h4 = hp[k4];            // broadcast read, conflict-free
            a0 = fdot2(wh[k4].x, h4.x, a0);
            a1 = fdot2(wh[k4].y, h4.y, a1);
            a2 = fdot2(wh[k4].z, h4.z, a2);
            a3 = fdot2(wh[k4].w, h4.w, a3);
        }
        if (t < ILEN) {
            const uint4* xp = (const uint4*)x_sh;
            #pragma unroll
            for (int k4 = 0; k4 < IDIM / 8; ++k4) {
                uint4 x4 = xp[k4];
                a0 = fdot2(wi[k4].x, x4.x, a0);
                a1 = fdot2(wi[k4].y, x4.y, a1);
                a2 = fdot2(wi[k4].z, x4.z, a2);
                a3 = fdot2(wi[k4].w, x4.w, a3);
            }
        }
        z_sh[tid] = (a0 + a1) + (a2 + a3);
        __syncthreads();   // z ready

        // wave 0 (tid<64) combines gates, updates c/h, publishes h slice
        if (tid < UNITS_PB) {
            float zi = z_sh[tid];
            float zf = z_sh[tid + UNITS_PB];
            float zg = z_sh[tid + 2 * UNITS_PB];
            float zo = z_sh[tid + 3 * UNITS_PB];
            float ig = sigm(zi);
            float fg = sigm(zf);
            float gg = tanh_fast(zg);
            float og = sigm(zo);
            c = fg * c + ig * gg;
            float hn = og * tanh_fast(c);
            __half hh = __float2half(hn);
            hn_sh[tid] = hh;
            if (t >= ILEN) {
                Hs[((size_t)bb * TLEN + (t - ILEN)) * HDIM + q * UNITS_PB + tid] = hh;
            }
        }
        // same wave: pack pairs and store to global h buffer (agent scope)
        if (tid < UNITS_PB / 2) {
            u32 v = ((const u32*)hn_sh)[tid];   // wave-local LDS RAW, hw-ordered
            __hip_atomic_store(&hg[((t + 1) & 1) * (HDIM / 2) + q * (UNITS_PB / 2) + tid],
                               v, __ATOMIC_RELAXED, __HIP_MEMORY_SCOPE_AGENT);
        }
        if (tid == 0) {
            // release: orders the 32 h-stores above
            __hip_atomic_fetch_add(flag, 1u, __ATOMIC_RELEASE, __HIP_MEMORY_SCOPE_AGENT);
            if (t + 1 < TTOT) {
                u32 target = (u32)NSPLIT * (u32)(t + 1);
                while (__hip_atomic_load(flag, __ATOMIC_ACQUIRE, __HIP_MEMORY_SCOPE_AGENT) < target) {
                    __builtin_amdgcn_s_sleep(1);
                }
            }
        }
        __syncthreads();   // all siblings done step t; safe to refresh h_sh

        if (t + 1 < TTOT) {
            if (tid < HDIM / 2) {
                h_sh[tid] = __hip_atomic_load(&hg[((t + 1) & 1) * (HDIM / 2) + tid],
                                              __ATOMIC_RELAXED, __HIP_MEMORY_SCOPE_AGENT);
            }
            // next iteration's first __syncthreads publishes h_sh block-wide
        }
    }
}

// ---------------------------------------------------------------------------
// Classifier: out[b][t][n] = clf_b[n] + clf_w[n]·h[b][t].
// ---------------------------------------------------------------------------
#define CTT 16
__global__ __launch_bounds__(256) void clf_kernel(
    const uint4* __restrict__ Wcq,
    const __half* __restrict__ Hs,
    const float* __restrict__ clf_b,
    float* __restrict__ out)
{
    __shared__ alignas(16) u32 h_sh[CTT * (HDIM / 2)];   // 8 KB
    const int tid = threadIdx.x;
    const int b  = blockIdx.x >> 6;
    const int t0 = (blockIdx.x & 63) * CTT;

    const uint4* hsrc = (const uint4*)(Hs + ((size_t)b * TLEN + t0) * HDIM);
    uint4* hdst = (uint4*)h_sh;
    hdst[tid]       = hsrc[tid];
    hdst[tid + 256] = hsrc[tid + 256];
    __syncthreads();

    const int n  = tid & (NCLS - 1);
    const int tl = tid >> 7;
    const float bias = clf_b[n];
    float acc[8];
    #pragma unroll
    for (int q = 0; q < 8; ++q) acc[q] = bias;

    #pragma unroll 4
    for (int k4 = 0; k4 < HDIM / 8; ++k4) {
        uint4 w = Wcq[k4 * NCLS + n];
        #pragma unroll
        for (int q = 0; q < 8; ++q) {
            const uint4* hp = (const uint4*)(h_sh + (tl + 2 * q) * (HDIM / 2));
            uint4 h = hp[k4];
            acc[q] = fdot2(w.x, h.x, acc[q]);
            acc[q] = fdot2(w.y, h.y, acc[q]);
            acc[q] = fdot2(w.z, h.z, acc[q]);
            acc[q] = fdot2(w.w, h.w, acc[q]);
        }
    }
    #pragma unroll
    for (int q = 0; q < 8; ++q) {
        out[((size_t)b * TLEN + t0 + tl + 2 * q) * NCLS + n] = acc[q];
    }
}

// ---------------------------------------------------------------------------
extern "C" void kernel_launch(void* const* d_in, const int* in_sizes, int n_in,
                              void* d_out, int out_size, void* d_ws, size_t ws_size,
                              hipStream_t stream)
{
    const float* inp   = (const float*)d_in[0];
    // d_in[1] = tlen (1024, hardcoded)
    const float* w_ih  = (const float*)d_in[2];
    const float* w_hh  = (const float*)d_in[3];
    const float* bias  = (const float*)d_in[4];
    const float* clf_w = (const float*)d_in[5];
    const float* clf_b = (const float*)d_in[6];
    float* out = (float*)d_out;

    char* ws = (char*)d_ws;
    uint4*  Whq   = (uint4*)(ws);                    // 512 KB
    uint4*  Wiq   = (uint4*)(ws + 524288);           // 256 KB
    uint4*  Wcq   = (uint4*)(ws + 786432);           // 64 KB
    __half* Hs    = (__half*)(ws + 851968);          // 33.55 MB
    u32*    hglob = (u32*)(ws + 851968 + 33554432);  // 64 KB
    u32*    flags = (u32*)(ws + 851968 + 33554432 + 65536);  // 8 KB

    init_kernel<<<64, 256, 0, stream>>>(hglob, flags);
    pack_kernel<<<208, 256, 0, stream>>>(w_ih, w_hh, clf_w, Whq, Wiq, Wcq);

    void* args[] = {(void*)&inp, (void*)&bias, (void*)&Whq, (void*)&Wiq,
                    (void*)&Hs, (void*)&hglob, (void*)&flags};
    hipLaunchCooperativeKernel((const void*)lstm_rec,
                               dim3(BSZ * NSPLIT), dim3(256), args, 0, stream);

    clf_kernel<<<BSZ * (TLEN / CTT), 256, 0, stream>>>(Wcq, Hs, clf_b, out);
}